// Round 3
// 546.305 us; speedup vs baseline: 1.0396x; 1.0396x over previous
//
#include <hip/hip_runtime.h>

// Problem constants (match reference)
#define C_CLS 151        // NUM_OBJ_CLS
#define NE    150        // C_CLS - 1
#define PATH  2048       // PATH_DIM
#define INF   600        // 4*NE
#define B_IMG 128
#define P_PAIR 512
#define NROWS (B_IMG * P_PAIR)   // 65536

// Native clang vector type — __builtin_nontemporal_store requires this
// (HIP's float4 is a class and is rejected by the builtin).
typedef float f32x4 __attribute__((ext_vector_type(4)));

// Workspace layout (byte offsets)
#define WT_OFF   0                        // Wt[600][2048] f32 (transposed lin_w)
#define SYM_OFF  4915200                  // sym[151][151] f32 (padded to 22816 floats)
#define A0_OFF   5006464                  // A0[150][2048] f32 (Full0 + onehot col + bias)
#define A1_OFF   6235264                  // A1[150][2048] f32 (Full1 + onehot col)
#define MC_OFF   7464064                  // miss_count[128] int
#define ML_OFF   7464576                  // miss_list[128][160] int

// ---- K1: transpose lin_w [2048 x 600] -> Wt [600 x 2048] ----
__global__ void k_transpose(const float* __restrict__ w, float* __restrict__ wt) {
    int idx = blockIdx.x * 256 + threadIdx.x;          // over 600*2048
    if (idx >= INF * PATH) return;
    int d = idx & (PATH - 1);
    int j = idx >> 11;
    wt[idx] = w[d * INF + j];   // write coalesced; read gathered (L2-cached, 4.9MB)
}

// ---- K2: sym = (score + score^T) * 0.5 ----
__global__ void k_sym(const float* __restrict__ score, float* __restrict__ sym) {
    int idx = blockIdx.x * 256 + threadIdx.x;
    if (idx >= C_CLS * C_CLS) return;
    int i = idx / C_CLS, j = idx % C_CLS;
    sym[idx] = 0.5f * (score[i * C_CLS + j] + score[j * C_CLS + i]);
}

// ---- K3: per-image missing-class lists ----
__global__ void k_miss(const int* __restrict__ pairs, int* __restrict__ mcount,
                       int* __restrict__ mlist) {
    __shared__ int flag[C_CLS];
    __shared__ int cnt;
    int b = blockIdx.x, tid = threadIdx.x;
    if (tid < C_CLS) flag[tid] = 0;
    if (tid == 0) cnt = 0;
    __syncthreads();
    const int* pp = pairs + b * (P_PAIR * 2);
    for (int i = tid; i < P_PAIR * 2; i += 256) flag[pp[i]] = 1;   // benign races
    __syncthreads();
    if (tid >= 1 && tid < C_CLS && flag[tid] == 0) {
        int pos = atomicAdd(&cnt, 1);
        mlist[b * 160 + pos] = tid;
    }
    __syncthreads();
    if (tid == 0) mcount[b] = cnt;
}

// ---- K4: A0[a][d] = bias[d] + Wt[300+a][d] + sum_c sym[a+1][c+1]*Wt[c][d]
//          A1[a][d] =           Wt[450+a][d] + sum_c sym[a+1][c+1]*Wt[150+c][d]
// grid: x = d-chunk (8), y = a-chunk of 10 (15), z = table (2). block = 256.
__global__ __launch_bounds__(256) void k_tables(const float* __restrict__ wt,
                                                const float* __restrict__ sym,
                                                const float* __restrict__ bias,
                                                float* __restrict__ A0,
                                                float* __restrict__ A1) {
    __shared__ float s[10 * NE];
    int tid = threadIdx.x;
    int d = blockIdx.x * 256 + tid;
    int abase = blockIdx.y * 10;
    int t = blockIdx.z;
    for (int i = tid; i < 10 * NE; i += 256) {
        int u = i / NE, c = i % NE;
        s[i] = sym[(abase + u + 1) * C_CLS + (c + 1)];
    }
    __syncthreads();
    float acc[10];
#pragma unroll
    for (int u = 0; u < 10; ++u) acc[u] = 0.f;
    const float* wrow = wt + (size_t)(t * NE) * PATH + d;
    for (int c = 0; c < NE; ++c) {
        float w = wrow[(size_t)c * PATH];
#pragma unroll
        for (int u = 0; u < 10; ++u) acc[u] += s[u * NE + c] * w;
    }
    float* A = t ? A1 : A0;
    int ohbase = t ? 450 : 300;
#pragma unroll
    for (int u = 0; u < 10; ++u) {
        int ia = abase + u;
        float v = acc[u] + wt[(size_t)(ohbase + ia) * PATH + d];
        if (!t) v += bias[d];
        A[(size_t)ia * PATH + d] = v;
    }
}

// ---- K5: out[row][d] = A0[p0-1][d] + A1[p1-1][d] - corrections ----
// Output stores are NON-TEMPORAL: the 512 MiB write stream must not
// write-allocate in L2, or it evicts the 2.4 MB A0/A1 tables and turns
// the 1 GiB of row re-reads into L3/HBM traffic (~+100 us).
__global__ __launch_bounds__(256) void k_out(const int* __restrict__ pairs,
                                             const float* __restrict__ A0,
                                             const float* __restrict__ A1,
                                             const float* __restrict__ sym,
                                             const float* __restrict__ wt,
                                             const int* __restrict__ mcount,
                                             const int* __restrict__ mlist,
                                             float* __restrict__ out) {
    int row = blockIdx.x;           // 0..65535
    int b = row >> 9;
    int tid = threadIdx.x;
    int p0 = pairs[row * 2 + 0];
    int p1 = pairs[row * 2 + 1];
    const f32x4* r0 = (const f32x4*)(A0 + (size_t)(p0 - 1) * PATH);
    const f32x4* r1 = (const f32x4*)(A1 + (size_t)(p1 - 1) * PATH);
    f32x4* o = (f32x4*)(out + (size_t)row * PATH);
    int kb = mcount[b];
#pragma unroll
    for (int h = 0; h < 2; ++h) {
        int i = h * 256 + tid;                 // float4 index 0..511
        f32x4 a = r0[i];
        f32x4 c = r1[i];
        f32x4 v = a + c;
        for (int m = 0; m < kb; ++m) {         // rare: ~0.16 classes/image missing
            int cls = mlist[b * 160 + m];
            float s0 = sym[p0 * C_CLS + cls];
            float s1 = sym[p1 * C_CLS + cls];
            f32x4 w0 = ((const f32x4*)(wt + (size_t)(cls - 1) * PATH))[i];
            f32x4 w1 = ((const f32x4*)(wt + (size_t)(NE + cls - 1) * PATH))[i];
            v -= s0 * w0 + s1 * w1;
        }
        __builtin_nontemporal_store(v, &o[i]);
    }
}

extern "C" void kernel_launch(void* const* d_in, const int* in_sizes, int n_in,
                              void* d_out, int out_size, void* d_ws, size_t ws_size,
                              hipStream_t stream) {
    const int*   pairs = (const int*)d_in[0];
    const float* score = (const float*)d_in[1];
    const float* lin_w = (const float*)d_in[2];
    const float* lin_b = (const float*)d_in[3];
    float* out = (float*)d_out;

    char* ws = (char*)d_ws;
    float* wt  = (float*)(ws + WT_OFF);
    float* sym = (float*)(ws + SYM_OFF);
    float* A0  = (float*)(ws + A0_OFF);
    float* A1  = (float*)(ws + A1_OFF);
    int*   mc  = (int*)(ws + MC_OFF);
    int*   ml  = (int*)(ws + ML_OFF);

    // Prep (independent, stream-serialized)
    k_transpose<<<(INF * PATH + 255) / 256, 256, 0, stream>>>(lin_w, wt);
    k_sym<<<(C_CLS * C_CLS + 255) / 256, 256, 0, stream>>>(score, sym);
    k_miss<<<B_IMG, 256, 0, stream>>>(pairs, mc, ml);

    // Tables: A0/A1 [150 x 2048]
    dim3 tg(PATH / 256, NE / 10, 2);
    k_tables<<<tg, 256, 0, stream>>>(wt, sym, lin_b, A0, A1);

    // Final gather-add: 65536 rows x 2048
    k_out<<<NROWS, 256, 0, stream>>>(pairs, A0, A1, sym, wt, mc, ml, out);
}